// Round 1
// baseline (1307.211 us; speedup 1.0000x reference)
//
#include <hip/hip_runtime.h>
#include <math.h>

#define T_SEQ 2048
#define DIM   1024
#define HD3   3072
#define NH    16
#define HD    64
#define EPSF  1e-4f

// ---------- helpers ----------
__device__ __forceinline__ float blockSum(float v, float* s4) {
#pragma unroll
  for (int o = 32; o > 0; o >>= 1) v += __shfl_xor(v, o, 64);
  __syncthreads();
  if ((threadIdx.x & 63) == 0) s4[threadIdx.x >> 6] = v;
  __syncthreads();
  return s4[0] + s4[1] + s4[2] + s4[3];
}

// ---------- 1) logmap(ref, x) ; also emit ref to d_out ----------
__global__ void logmap_kernel(const float* __restrict__ x,
                              float* __restrict__ xhyp,
                              float* __restrict__ ref_out) {
  __shared__ float s4[4];
  int t = blockIdx.x;
  const float* xt = x + (size_t)t * DIM;
  float xe[4], re[4];
  float xn2 = 0.f, yn2 = 0.f, ip = 0.f;
#pragma unroll
  for (int i = 0; i < 4; i++) {
    int e = threadIdx.x + i * 256;
    float xv = xt[e];
    float rv = (t > 0) ? xt[e - DIM] : 0.f;
    xe[i] = xv; re[i] = rv;
    yn2 += xv * xv;
    xn2 += rv * rv;
    ip  -= rv * xv;               // ip = (-ref)·x
    ref_out[(size_t)t * DIM + e] = rv;
  }
  xn2 = blockSum(xn2, s4);
  yn2 = blockSum(yn2, s4);
  ip  = blockSum(ip,  s4);
  // mobius_add(-ref, x):  num = a*(-ref) + b*x,  den
  float a = 1.f + 2.f * ip + yn2;   // c = 1
  float b = 1.f - xn2;
  float den = fmaxf(1.f + 2.f * ip + xn2 * yn2, EPSF);
  float invden = 1.f / den;
  float mob[4];
  float mn2 = 0.f;
#pragma unroll
  for (int i = 0; i < 4; i++) {
    float m = (-a * re[i] + b * xe[i]) * invden;
    mob[i] = m;
    mn2 += m * m;
  }
  mn2 = blockSum(mn2, s4);
  float mn  = sqrtf(mn2);
  float sf  = 2.f / (1.f + xn2);
  float cf  = 2.f / (sf + EPSF);
  float arg = fminf(sqrtf(mn), 0.99f);     // clip(sqrt(c*mn), -.99, .99), mn>=0
  float mult = cf * atanhf(arg) / (mn + EPSF);
#pragma unroll
  for (int i = 0; i < 4; i++)
    xhyp[(size_t)t * DIM + threadIdx.x + i * 256] = mult * mob[i];
}

// ---------- 2/5) C[M][N] = A[M][K] * W[N][K]^T  (f32, 64x64 tile) ----------
__global__ __launch_bounds__(256) void gemm_abt(const float* __restrict__ A,
                                                const float* __restrict__ W,
                                                float* __restrict__ C,
                                                int M, int N, int K) {
  __shared__ float As[16][65];   // +1 pad: conflict-free stores/reads
  __shared__ float Ws[16][65];
  int tid = threadIdx.x;
  int tx = tid & 15, ty = tid >> 4;
  int bm = blockIdx.y * 64, bn = blockIdx.x * 64;
  float acc[4][4] = {};
  for (int kt = 0; kt < K; kt += 16) {
#pragma unroll
    for (int i = 0; i < 4; i++) {
      int e = tid + i * 256;
      int r = e >> 4, kk = e & 15;
      As[kk][r] = A[(size_t)(bm + r) * K + kt + kk];
      Ws[kk][r] = W[(size_t)(bn + r) * K + kt + kk];
    }
    __syncthreads();
#pragma unroll
    for (int kk = 0; kk < 16; kk++) {
      float av[4], wv[4];
#pragma unroll
      for (int i = 0; i < 4; i++) av[i] = As[kk][ty * 4 + i];
#pragma unroll
      for (int j = 0; j < 4; j++) wv[j] = Ws[kk][tx * 4 + j];
#pragma unroll
      for (int i = 0; i < 4; i++)
#pragma unroll
        for (int j = 0; j < 4; j++) acc[i][j] += av[i] * wv[j];
    }
    __syncthreads();
  }
#pragma unroll
  for (int i = 0; i < 4; i++)
#pragma unroll
    for (int j = 0; j < 4; j++)
      C[(size_t)(bm + ty * 4 + i) * N + bn + tx * 4 + j] = acc[i][j];
}

// ---------- 3) RMS-norm + rotary for q,k ; one wave per (t,h) ----------
__global__ void rmsrot_kernel(const float* __restrict__ qkv,
                              float* __restrict__ qout,   // [H][T][64]
                              float* __restrict__ kTout)  // [H][64][T]
{
  int t = blockIdx.x;
  int w = threadIdx.x >> 6;
  int lane = threadIdx.x & 63;
  int h = blockIdx.y * 4 + w;
  const float* base = qkv + (size_t)t * HD3;
  float qv = base[h * HD + lane];
  float kv = base[DIM + h * HD + lane];
  float qs = qv * qv, ks = kv * kv;
#pragma unroll
  for (int o = 32; o > 0; o >>= 1) {
    qs += __shfl_xor(qs, o, 64);
    ks += __shfl_xor(ks, o, 64);
  }
  float qn = qv * rsqrtf(qs * (1.f / 64.f) + 1.1920929e-07f);
  float kn = kv * rsqrtf(ks * (1.f / 64.f) + 1.1920929e-07f);
  int j = lane & 31;
  float cth = 1.f, sth = 0.f;
  if (j < 16) {
    float freq = exp2f(-(10.f / 15.f) * (float)j);  // (1/1024)^(j/15)
    float th = (float)t * freq;
    cth = cosf(th);
    sth = sinf(th);
  }
  float qp = __shfl_xor(qn, 32, 64);
  float kp = __shfl_xor(kn, 32, 64);
  float sgn = (lane < 32) ? 1.f : -1.f;
  float qr = qn * cth + sgn * qp * sth;
  float kr = kn * cth + sgn * kp * sth;
  qout[((size_t)h * T_SEQ + t) * HD + lane] = qr;
  kTout[((size_t)h * HD + lane) * T_SEQ + t] = kr;
}

// ---------- 4) causal flash attention, one wave per query ----------
__global__ __launch_bounds__(256) void attn_kernel(const float* __restrict__ q,
                                                   const float* __restrict__ kT,
                                                   const float* __restrict__ qkv, // V lives here
                                                   float* __restrict__ o) {
  int w = threadIdx.x >> 6;
  int lane = threadIdx.x & 63;
  int qi = blockIdx.x * 4 + w;
  int h = blockIdx.y;
  float qv = q[((size_t)h * T_SEQ + qi) * HD + lane];
  float m = -INFINITY, l = 0.f, od = 0.f;
  int nkb = (qi >> 6) + 1;
  const float* kTh = kT + (size_t)h * HD * T_SEQ;
  for (int kb = 0; kb < nkb; kb++) {
    int key = kb * 64 + lane;
    float s = 0.f;
    const float* kp = kTh + kb * 64 + lane;
#pragma unroll 16
    for (int d = 0; d < 64; d++) {
      float qd = __shfl(qv, d, 64);
      s += qd * kp[(size_t)d * T_SEQ];
    }
    s *= 0.12f;
    if (key > qi) s = -INFINITY;
    float sm = s;
#pragma unroll
    for (int off = 32; off > 0; off >>= 1) sm = fmaxf(sm, __shfl_xor(sm, off, 64));
    float m_new = fmaxf(m, sm);
    float scale = expf(m - m_new);   // exp(-inf)=0 on first tile
    float p = expf(s - m_new);       // masked lanes -> 0
    float ps = p;
#pragma unroll
    for (int off = 32; off > 0; off >>= 1) ps += __shfl_xor(ps, off, 64);
    l = l * scale + ps;
    od *= scale;
    const float* vp = qkv + (size_t)(kb * 64) * HD3 + 2 * DIM + h * HD + lane;
#pragma unroll 16
    for (int jj = 0; jj < 64; jj++) {
      float pj = __shfl(p, jj, 64);
      od += pj * vp[(size_t)jj * HD3];
    }
    m = m_new;
  }
  o[(size_t)qi * DIM + h * HD + lane] = od / l;
}

// ---------- 6) expmap(ref, y) ----------
__global__ void expmap_kernel(const float* __restrict__ y2,
                              const float* __restrict__ ref,
                              float* __restrict__ yout) {
  __shared__ float s4[4];
  int t = blockIdx.x;
  float xe[4], ve[4];
  float xn2 = 0.f, vn2 = 0.f, xv = 0.f;
#pragma unroll
  for (int i = 0; i < 4; i++) {
    int e = threadIdx.x + i * 256;
    float X = ref[(size_t)t * DIM + e];
    float V = y2[(size_t)t * DIM + e];
    xe[i] = X; ve[i] = V;
    xn2 += X * X; vn2 += V * V; xv += X * V;
  }
  xn2 = blockSum(xn2, s4);
  vn2 = blockSum(vn2, s4);
  xv  = blockSum(xv,  s4);
  float vn  = sqrtf(vn2);
  float sf  = 2.f / (1.f + xn2);
  float arg = sqrtf(fminf(fmaxf(0.5f * sf * vn2, 0.f), 8.f));
  float scl = tanhf(arg) / (vn + EPSF);      // second = scl * v   (1/sqrt(c)=1)
  float yn2 = scl * scl * vn2;
  float ip  = scl * xv;
  float A = 1.f + 2.f * ip + yn2;
  float B = (1.f - xn2) * scl;
  float den = fmaxf(1.f + 2.f * ip + xn2 * yn2, EPSF);
  float invden = 1.f / den;
#pragma unroll
  for (int i = 0; i < 4; i++)
    yout[(size_t)t * DIM + threadIdx.x + i * 256] = (A * xe[i] + B * ve[i]) * invden;
}

// ---------- launch ----------
extern "C" void kernel_launch(void* const* d_in, const int* in_sizes, int n_in,
                              void* d_out, int out_size, void* d_ws, size_t ws_size,
                              hipStream_t stream) {
  const float* x        = (const float*)d_in[0];
  const float* qkv_w    = (const float*)d_in[1];
  const float* c_proj_w = (const float*)d_in[2];
  float* out = (float*)d_out;
  float* ws  = (float*)d_ws;

  // workspace layout (floats): 48 MB total, with reuse
  float* xhyp = ws;                 // [0, 2M)       reused as attn output o
  float* qkv  = ws + 2097152;       // [2M, 8M)      q|k|v projections
  float* qrot = ws + 8388608;       // [8M, 10M)     reused as y2
  float* kT   = ws + 10485760;      // [10M, 12M)    K transposed [H][64][T]
  float* o    = xhyp;
  float* y2   = qrot;
  float* ref  = out + 2097152;      // second output

  logmap_kernel<<<T_SEQ, 256, 0, stream>>>(x, xhyp, ref);
  gemm_abt<<<dim3(HD3 / 64, T_SEQ / 64), 256, 0, stream>>>(xhyp, qkv_w, qkv, T_SEQ, HD3, DIM);
  rmsrot_kernel<<<dim3(T_SEQ, 4), 256, 0, stream>>>(qkv, qrot, kT);
  attn_kernel<<<dim3(T_SEQ / 4, NH), 256, 0, stream>>>(qrot, kT, qkv, o);
  gemm_abt<<<dim3(DIM / 64, T_SEQ / 64), 256, 0, stream>>>(o, c_proj_w, y2, T_SEQ, DIM, DIM);
  expmap_kernel<<<T_SEQ, 256, 0, stream>>>(y2, ref, out);
}

// Round 2
// 208.983 us; speedup vs baseline: 6.2551x; 6.2551x over previous
//
#include <hip/hip_runtime.h>
#include <math.h>

#define T_SEQ 2048
#define DIM   1024
#define HD3   3072
#define NH    16
#define HD    64
#define EPSF  1e-4f
#define MB    1048576

typedef __attribute__((ext_vector_type(8))) short bf16x8;
typedef __attribute__((ext_vector_type(4))) float f32x4;

__device__ __forceinline__ ushort f2bf(float f) {
  unsigned int u = __float_as_uint(f);
  unsigned int r = (u + 0x7FFFu + ((u >> 16) & 1u)) >> 16;
  return (ushort)r;
}

#define GLOAD(gp, lp) __builtin_amdgcn_global_load_lds( \
    (const __attribute__((address_space(1))) unsigned int*)(gp), \
    (__attribute__((address_space(3))) unsigned int*)(lp), 16, 0, 0)

// ---------- helpers ----------
__device__ __forceinline__ float blockSum(float v, float* s4) {
#pragma unroll
  for (int o = 32; o > 0; o >>= 1) v += __shfl_xor(v, o, 64);
  __syncthreads();
  if ((threadIdx.x & 63) == 0) s4[threadIdx.x >> 6] = v;
  __syncthreads();
  return s4[0] + s4[1] + s4[2] + s4[3];
}

// ---------- 0) f32 -> bf16 convert ----------
__global__ void cvt_kernel(const float* __restrict__ src, ushort* __restrict__ dst, int n8) {
  int i = blockIdx.x * 256 + threadIdx.x;
  if (i >= n8) return;
  float4 a = ((const float4*)src)[i * 2];
  float4 b = ((const float4*)src)[i * 2 + 1];
  bf16x8 v;
  v[0] = f2bf(a.x); v[1] = f2bf(a.y); v[2] = f2bf(a.z); v[3] = f2bf(a.w);
  v[4] = f2bf(b.x); v[5] = f2bf(b.y); v[6] = f2bf(b.z); v[7] = f2bf(b.w);
  *(bf16x8*)(dst + (size_t)i * 8) = v;
}

// ---------- 1) logmap(ref, x) -> bf16 xhyp ; also emit ref (f32) ----------
__global__ void logmap_kernel(const float* __restrict__ x,
                              ushort* __restrict__ xhyp,
                              float* __restrict__ ref_out) {
  __shared__ float s4[4];
  int t = blockIdx.x;
  const float* xt = x + (size_t)t * DIM;
  float xe[4], re[4];
  float xn2 = 0.f, yn2 = 0.f, ip = 0.f;
#pragma unroll
  for (int i = 0; i < 4; i++) {
    int e = threadIdx.x + i * 256;
    float xv = xt[e];
    float rv = (t > 0) ? xt[e - DIM] : 0.f;
    xe[i] = xv; re[i] = rv;
    yn2 += xv * xv;
    xn2 += rv * rv;
    ip  -= rv * xv;
    ref_out[(size_t)t * DIM + e] = rv;
  }
  xn2 = blockSum(xn2, s4);
  yn2 = blockSum(yn2, s4);
  ip  = blockSum(ip,  s4);
  float a = 1.f + 2.f * ip + yn2;
  float b = 1.f - xn2;
  float den = fmaxf(1.f + 2.f * ip + xn2 * yn2, EPSF);
  float invden = 1.f / den;
  float mob[4];
  float mn2 = 0.f;
#pragma unroll
  for (int i = 0; i < 4; i++) {
    float m = (-a * re[i] + b * xe[i]) * invden;
    mob[i] = m;
    mn2 += m * m;
  }
  mn2 = blockSum(mn2, s4);
  float mn  = sqrtf(mn2);
  float sf  = 2.f / (1.f + xn2);
  float cf  = 2.f / (sf + EPSF);
  float arg = fminf(sqrtf(mn), 0.99f);
  float mult = cf * atanhf(arg) / (mn + EPSF);
#pragma unroll
  for (int i = 0; i < 4; i++)
    xhyp[(size_t)t * DIM + threadIdx.x + i * 256] = f2bf(mult * mob[i]);
}

// ---------- 2/5) C[M][N] = A[M][K] * W[N][K]^T  (bf16 MFMA, f32 out) ----------
__global__ __launch_bounds__(256) void gemm_bf16(const ushort* __restrict__ A,
                                                 const ushort* __restrict__ W,
                                                 float* __restrict__ C,
                                                 int M, int N, int K) {
  __shared__ ushort As[128 * 32];
  __shared__ ushort Bs[128 * 32];
  int tid = threadIdx.x;
  int lane = tid & 63, w = tid >> 6;
  int wr = w >> 1, wc = w & 1;
  int g = lane >> 4, cc = lane & 15;
  int bm = blockIdx.y * 128, bn = blockIdx.x * 128;
  f32x4 acc[4][4] = {};
  for (int kt = 0; kt < K; kt += 32) {
#pragma unroll
    for (int i = 0; i < 2; i++) {
      int ch = (w * 2 + i) * 64 + lane;
      int row = ch >> 2, c8 = (ch & 3) * 8;
      GLOAD(A + (size_t)(bm + row) * K + kt + c8, &As[(w * 2 + i) * 512]);
      GLOAD(W + (size_t)(bn + row) * K + kt + c8, &Bs[(w * 2 + i) * 512]);
    }
    __syncthreads();
    bf16x8 af[4], bfr[4];
#pragma unroll
    for (int m = 0; m < 4; m++)
      af[m] = *(const bf16x8*)&As[(wr * 64 + m * 16 + cc) * 32 + 8 * g];
#pragma unroll
    for (int n = 0; n < 4; n++)
      bfr[n] = *(const bf16x8*)&Bs[(wc * 64 + n * 16 + cc) * 32 + 8 * g];
#pragma unroll
    for (int m = 0; m < 4; m++)
#pragma unroll
      for (int n = 0; n < 4; n++)
        acc[m][n] = __builtin_amdgcn_mfma_f32_16x16x32_bf16(af[m], bfr[n], acc[m][n], 0, 0, 0);
    __syncthreads();
  }
#pragma unroll
  for (int m = 0; m < 4; m++)
#pragma unroll
    for (int n = 0; n < 4; n++)
#pragma unroll
      for (int j = 0; j < 4; j++)
        C[(size_t)(bm + wr * 64 + m * 16 + g * 4 + j) * N + bn + wc * 64 + n * 16 + cc] = acc[m][n][j];
}

// ---------- 3) RMS-norm + rotary -> bf16 q,k in [h][t][64] ----------
__global__ void rmsrot_kernel(const float* __restrict__ qkv,
                              ushort* __restrict__ qb,
                              ushort* __restrict__ kb) {
  int t = blockIdx.x;
  int w = threadIdx.x >> 6;
  int lane = threadIdx.x & 63;
  int h = blockIdx.y * 4 + w;
  const float* base = qkv + (size_t)t * HD3;
  float qv = base[h * HD + lane];
  float kv = base[DIM + h * HD + lane];
  float qs = qv * qv, ks = kv * kv;
#pragma unroll
  for (int o = 32; o > 0; o >>= 1) {
    qs += __shfl_xor(qs, o, 64);
    ks += __shfl_xor(ks, o, 64);
  }
  float qn = qv * rsqrtf(qs * (1.f / 64.f) + 1.1920929e-07f);
  float kn = kv * rsqrtf(ks * (1.f / 64.f) + 1.1920929e-07f);
  int j = lane & 31;
  float cth = 1.f, sth = 0.f;
  if (j < 16) {
    float freq = exp2f(-(10.f / 15.f) * (float)j);
    float th = (float)t * freq;
    cth = cosf(th);
    sth = sinf(th);
  }
  float qp = __shfl_xor(qn, 32, 64);
  float kp = __shfl_xor(kn, 32, 64);
  float sgn = (lane < 32) ? 1.f : -1.f;
  float qr = qn * cth + sgn * qp * sth;
  float kr = kn * cth + sgn * kp * sth;
  qb[((size_t)h * T_SEQ + t) * HD + lane] = f2bf(qr);
  kb[((size_t)h * T_SEQ + t) * HD + lane] = f2bf(kr);
}

// ---------- 3b) V transpose -> bf16 vT [h][64][T] ----------
__global__ void vtrans_kernel(const float* __restrict__ qkv, ushort* __restrict__ vt) {
  __shared__ ushort tile[64][68];
  int h = blockIdx.y, tt = blockIdx.x;
  int d = threadIdx.x & 63, tr = threadIdx.x >> 6;
#pragma unroll
  for (int i = 0; i < 16; i++) {
    int t = tt * 64 + tr + i * 4;
    tile[d][tr + i * 4] = f2bf(qkv[(size_t)t * HD3 + 2 * DIM + h * HD + d]);
  }
  __syncthreads();
  int td = threadIdx.x & 63, dr = threadIdx.x >> 6;
#pragma unroll
  for (int i = 0; i < 16; i++) {
    int dd = dr + i * 4;
    vt[((size_t)h * HD + dd) * T_SEQ + tt * 64 + td] = tile[dd][td];
  }
}

// ---------- 4) causal flash attention, MFMA, one wave per 16 queries ----------
__global__ __launch_bounds__(256) void attn_mfma(const ushort* __restrict__ qb,
                                                 const ushort* __restrict__ kb,
                                                 const ushort* __restrict__ vt,
                                                 ushort* __restrict__ o) {
  __shared__ ushort plds[4][512];
  int lane = threadIdx.x & 63, w = threadIdx.x >> 6;
  int g = lane >> 4, cc = lane & 15;
  int h = blockIdx.y;
  int qbase = (blockIdx.x * 4 + w) * 16;
  const ushort* qh = qb + (size_t)h * T_SEQ * HD;
  const ushort* kh = kb + (size_t)h * T_SEQ * HD;
  const ushort* vh = vt + (size_t)h * HD * T_SEQ;
  bf16x8 aq0 = *(const bf16x8*)&qh[(qbase + cc) * HD + 8 * g];
  bf16x8 aq1 = *(const bf16x8*)&qh[(qbase + cc) * HD + 32 + 8 * g];
  f32x4 acc[4] = {};
  float mrow[4] = {-1e30f, -1e30f, -1e30f, -1e30f};
  float lrow[4] = {0.f, 0.f, 0.f, 0.f};
  int nkb = qbase / 32 + 1;
  ushort* pl = plds[w];
  for (int kbi = 0; kbi < nkb; kbi++) {
    int k0 = kbi * 32;
    f32x4 c0 = {}, c1 = {};
    bf16x8 b00 = *(const bf16x8*)&kh[(k0 + cc) * HD + 8 * g];
    bf16x8 b01 = *(const bf16x8*)&kh[(k0 + cc) * HD + 32 + 8 * g];
    bf16x8 b10 = *(const bf16x8*)&kh[(k0 + 16 + cc) * HD + 8 * g];
    bf16x8 b11 = *(const bf16x8*)&kh[(k0 + 16 + cc) * HD + 32 + 8 * g];
    c0 = __builtin_amdgcn_mfma_f32_16x16x32_bf16(aq0, b00, c0, 0, 0, 0);
    c0 = __builtin_amdgcn_mfma_f32_16x16x32_bf16(aq1, b01, c0, 0, 0, 0);
    c1 = __builtin_amdgcn_mfma_f32_16x16x32_bf16(aq0, b10, c1, 0, 0, 0);
    c1 = __builtin_amdgcn_mfma_f32_16x16x32_bf16(aq1, b11, c1, 0, 0, 0);
    float s0[4], s1[4];
    bool lastt = (kbi == nkb - 1);
#pragma unroll
    for (int j = 0; j < 4; j++) {
      s0[j] = c0[j] * 0.12f;
      s1[j] = c1[j] * 0.12f;
      if (lastt) {
        int q = qbase + g * 4 + j;
        if (k0 + cc > q)      s0[j] = -1e30f;
        if (k0 + 16 + cc > q) s1[j] = -1e30f;
      }
    }
    float pm[4];
#pragma unroll
    for (int j = 0; j < 4; j++) pm[j] = fmaxf(s0[j], s1[j]);
#pragma unroll
    for (int off = 1; off < 16; off <<= 1)
#pragma unroll
      for (int j = 0; j < 4; j++) pm[j] = fmaxf(pm[j], __shfl_xor(pm[j], off, 64));
    float scl[4];
#pragma unroll
    for (int j = 0; j < 4; j++) {
      float mn = fmaxf(mrow[j], pm[j]);
      scl[j] = __expf(mrow[j] - mn);
      mrow[j] = mn;
      s0[j] = __expf(s0[j] - mn);
      s1[j] = __expf(s1[j] - mn);
    }
    float rs[4];
#pragma unroll
    for (int j = 0; j < 4; j++) rs[j] = s0[j] + s1[j];
#pragma unroll
    for (int off = 1; off < 16; off <<= 1)
#pragma unroll
      for (int j = 0; j < 4; j++) rs[j] += __shfl_xor(rs[j], off, 64);
#pragma unroll
    for (int j = 0; j < 4; j++) lrow[j] = lrow[j] * scl[j] + rs[j];
#pragma unroll
    for (int ds = 0; ds < 4; ds++)
#pragma unroll
      for (int j = 0; j < 4; j++) acc[ds][j] *= scl[j];
#pragma unroll
    for (int j = 0; j < 4; j++) {
      pl[(g * 4 + j) * 32 + cc]      = f2bf(s0[j]);
      pl[(g * 4 + j) * 32 + 16 + cc] = f2bf(s1[j]);
    }
    asm volatile("s_waitcnt lgkmcnt(0)" ::: "memory");
    bf16x8 pa = *(const bf16x8*)&pl[cc * 32 + 8 * g];
#pragma unroll
    for (int ds = 0; ds < 4; ds++) {
      bf16x8 bv = *(const bf16x8*)&vh[(size_t)(ds * 16 + cc) * T_SEQ + k0 + 8 * g];
      acc[ds] = __builtin_amdgcn_mfma_f32_16x16x32_bf16(pa, bv, acc[ds], 0, 0, 0);
    }
  }
  float inv[4];
#pragma unroll
  for (int j = 0; j < 4; j++) inv[j] = 1.f / lrow[j];
#pragma unroll
  for (int ds = 0; ds < 4; ds++)
#pragma unroll
    for (int j = 0; j < 4; j++)
      o[(size_t)(qbase + g * 4 + j) * DIM + h * HD + ds * 16 + cc] = f2bf(acc[ds][j] * inv[j]);
}

// ---------- 6) expmap(ref, y) ----------
__global__ void expmap_kernel(const float* __restrict__ y2,
                              const float* __restrict__ ref,
                              float* __restrict__ yout) {
  __shared__ float s4[4];
  int t = blockIdx.x;
  float xe[4], ve[4];
  float xn2 = 0.f, vn2 = 0.f, xv = 0.f;
#pragma unroll
  for (int i = 0; i < 4; i++) {
    int e = threadIdx.x + i * 256;
    float X = ref[(size_t)t * DIM + e];
    float V = y2[(size_t)t * DIM + e];
    xe[i] = X; ve[i] = V;
    xn2 += X * X; vn2 += V * V; xv += X * V;
  }
  xn2 = blockSum(xn2, s4);
  vn2 = blockSum(vn2, s4);
  xv  = blockSum(xv,  s4);
  float vn  = sqrtf(vn2);
  float sf  = 2.f / (1.f + xn2);
  float arg = sqrtf(fminf(fmaxf(0.5f * sf * vn2, 0.f), 8.f));
  float scl = tanhf(arg) / (vn + EPSF);
  float yn2 = scl * scl * vn2;
  float ip  = scl * xv;
  float A = 1.f + 2.f * ip + yn2;
  float B = (1.f - xn2) * scl;
  float den = fmaxf(1.f + 2.f * ip + xn2 * yn2, EPSF);
  float invden = 1.f / den;
#pragma unroll
  for (int i = 0; i < 4; i++)
    yout[(size_t)t * DIM + threadIdx.x + i * 256] = (A * xe[i] + B * ve[i]) * invden;
}

// ---------- launch ----------
extern "C" void kernel_launch(void* const* d_in, const int* in_sizes, int n_in,
                              void* d_out, int out_size, void* d_ws, size_t ws_size,
                              hipStream_t stream) {
  const float* x        = (const float*)d_in[0];
  const float* qkv_w    = (const float*)d_in[1];
  const float* c_proj_w = (const float*)d_in[2];
  float* out = (float*)d_out;
  char*  W   = (char*)d_ws;

  // workspace layout (bytes), 48 MB total with reuse
  ushort* qkvw_bf   = (ushort*)(W);             // [0, 6MB)
  ushort* cprojw_bf = (ushort*)(W + 6  * MB);   // [6, 8MB)
  ushort* xhyp_bf   = (ushort*)(W + 8  * MB);   // [8, 12MB)  reused as attn out o
  float*  qkvf      = (float*) (W + 12 * MB);   // [12, 36MB) reused as y2
  ushort* qbuf      = (ushort*)(W + 36 * MB);   // [36, 40MB)
  ushort* kbuf      = (ushort*)(W + 40 * MB);   // [40, 44MB)
  ushort* vtb       = (ushort*)(W + 44 * MB);   // [44, 48MB)
  ushort* obuf      = xhyp_bf;
  float*  y2        = qkvf;
  float*  ref       = out + (size_t)T_SEQ * DIM;

  cvt_kernel<<<1536, 256, 0, stream>>>(qkv_w, qkvw_bf, 393216);
  cvt_kernel<<<512, 256, 0, stream>>>(c_proj_w, cprojw_bf, 131072);
  logmap_kernel<<<T_SEQ, 256, 0, stream>>>(x, xhyp_bf, ref);
  gemm_bf16<<<dim3(HD3 / 128, T_SEQ / 128), 256, 0, stream>>>(xhyp_bf, qkvw_bf, qkvf, T_SEQ, HD3, DIM);
  rmsrot_kernel<<<dim3(T_SEQ, 4), 256, 0, stream>>>(qkvf, qbuf, kbuf);
  vtrans_kernel<<<dim3(T_SEQ / 64, NH), 256, 0, stream>>>(qkvf, vtb);
  attn_mfma<<<dim3(T_SEQ / 64, NH), 256, 0, stream>>>(qbuf, kbuf, vtb, obuf);
  gemm_bf16<<<dim3(DIM / 128, T_SEQ / 128), 256, 0, stream>>>(obuf, cprojw_bf, y2, T_SEQ, DIM, DIM);
  expmap_kernel<<<T_SEQ, 256, 0, stream>>>(y2, ref, out);
}